// Round 13
// baseline (4238.673 us; speedup 1.0000x reference)
//
#include <hip/hip_runtime.h>
#include <math.h>

#define N_RES 512
#define CS 384
#define CZ 128
#define HD 12
#define CH 16
#define QKV_DIM 1152   // 192 q + 384 kv + 144 qp + 432 kvp
#define CAT_DIM 2112   // 192 o + 288 fl + 96 norm + 1536 opair
#define INF_F 100000.0f

typedef __attribute__((ext_vector_type(8))) __bf16 bf16x8;
typedef __attribute__((ext_vector_type(4))) float f32x4;

__device__ inline bf16x8 cvt8(float4 a, float4 b) {
    bf16x8 r;
    r[0] = (__bf16)a.x; r[1] = (__bf16)a.y; r[2] = (__bf16)a.z; r[3] = (__bf16)a.w;
    r[4] = (__bf16)b.x; r[5] = (__bf16)b.y; r[6] = (__bf16)b.z; r[7] = (__bf16)b.w;
    return r;
}

// quat (w,x,y,z) -> rot rows r[9]
__device__ inline void quat_rot(float w, float x, float y, float z, float* r) {
    float n = 1.0f / sqrtf(w*w + x*x + y*y + z*z);
    w *= n; x *= n; y *= n; z *= n;
    r[0] = 1 - 2*(y*y + z*z); r[1] = 2*(x*y - w*z);     r[2] = 2*(x*z + w*y);
    r[3] = 2*(x*y + w*z);     r[4] = 1 - 2*(x*x + z*z); r[5] = 2*(y*z - w*x);
    r[6] = 2*(x*z - w*y);     r[7] = 2*(y*z + w*x);     r[8] = 1 - 2*(x*x + y*y);
}

// ---------------- MFMA bf16 GEMM (unchanged from round 8, measured) ---------------
__global__ __launch_bounds__(256) void gemm_mfma(
    const float* __restrict__ A, const float* __restrict__ W,
    const float* __restrict__ bias, const float* res, float* out,
    int M, int Nn, int K, int relu)
{
    __shared__ __bf16 Asl[64 * 64];
    __shared__ __bf16 Bsl[64 * 64];
    int bm = blockIdx.y * 64;
    int bn = blockIdx.x * 64;
    int tid = threadIdx.x;

    int tr = tid >> 2;
    int tu = (tid & 3) * 2;
    const float* ga0 = A + (size_t)(bm + tr) * K + tu * 8;
    const float* gb0 = W + (size_t)(bn + tr) * K + tu * 8;

    int lane = tid & 63;
    int w = tid >> 6;
    int wr = w >> 1, wc = w & 1;
    int lr = lane & 15, lg = lane >> 4;
    int arow0 = wr * 32 + lr, arow1 = arow0 + 16;
    int brow0 = wc * 32 + lr, brow1 = brow0 + 16;

    f32x4 acc00 = {0.f, 0.f, 0.f, 0.f}, acc01 = {0.f, 0.f, 0.f, 0.f};
    f32x4 acc10 = {0.f, 0.f, 0.f, 0.f}, acc11 = {0.f, 0.f, 0.f, 0.f};

    float4 ra0, ra1, ra2, ra3, rb0, rb1, rb2, rb3;
    ra0 = ((const float4*)ga0)[0]; ra1 = ((const float4*)ga0)[1];
    ra2 = ((const float4*)ga0)[2]; ra3 = ((const float4*)ga0)[3];
    rb0 = ((const float4*)gb0)[0]; rb1 = ((const float4*)gb0)[1];
    rb2 = ((const float4*)gb0)[2]; rb3 = ((const float4*)gb0)[3];

    int u0 = tu ^ (tr & 7);
    int u1 = (tu + 1) ^ (tr & 7);

    for (int k0 = 0; k0 < K; k0 += 64) {
        __syncthreads();
        *(bf16x8*)(Asl + tr * 64 + u0 * 8) = cvt8(ra0, ra1);
        *(bf16x8*)(Asl + tr * 64 + u1 * 8) = cvt8(ra2, ra3);
        *(bf16x8*)(Bsl + tr * 64 + u0 * 8) = cvt8(rb0, rb1);
        *(bf16x8*)(Bsl + tr * 64 + u1 * 8) = cvt8(rb2, rb3);
        __syncthreads();
        if (k0 + 64 < K) {
            const float* ga = ga0 + k0 + 64;
            const float* gb = gb0 + k0 + 64;
            ra0 = ((const float4*)ga)[0]; ra1 = ((const float4*)ga)[1];
            ra2 = ((const float4*)ga)[2]; ra3 = ((const float4*)ga)[3];
            rb0 = ((const float4*)gb)[0]; rb1 = ((const float4*)gb)[1];
            rb2 = ((const float4*)gb)[2]; rb3 = ((const float4*)gb)[3];
        }
        #pragma unroll
        for (int ks = 0; ks < 2; ++ks) {
            int ub = ks * 4 + lg;
            bf16x8 a0 = *(bf16x8*)(Asl + arow0 * 64 + (ub ^ (lr & 7)) * 8);
            bf16x8 a1 = *(bf16x8*)(Asl + arow1 * 64 + (ub ^ (lr & 7)) * 8);
            bf16x8 b0 = *(bf16x8*)(Bsl + brow0 * 64 + (ub ^ (lr & 7)) * 8);
            bf16x8 b1 = *(bf16x8*)(Bsl + brow1 * 64 + (ub ^ (lr & 7)) * 8);
            acc00 = __builtin_amdgcn_mfma_f32_16x16x32_bf16(a0, b0, acc00, 0, 0, 0);
            acc01 = __builtin_amdgcn_mfma_f32_16x16x32_bf16(a0, b1, acc01, 0, 0, 0);
            acc10 = __builtin_amdgcn_mfma_f32_16x16x32_bf16(a1, b0, acc10, 0, 0, 0);
            acc11 = __builtin_amdgcn_mfma_f32_16x16x32_bf16(a1, b1, acc11, 0, 0, 0);
        }
    }

    int mb = bm + wr * 32, nb = bn + wc * 32;
    #pragma unroll
    for (int fm = 0; fm < 2; ++fm) {
        #pragma unroll
        for (int fn = 0; fn < 2; ++fn) {
            f32x4 acc = fm == 0 ? (fn == 0 ? acc00 : acc01) : (fn == 0 ? acc10 : acc11);
            int n = nb + fn * 16 + lr;
            float bi = bias[n];
            int m0 = mb + fm * 16 + lg * 4;
            #pragma unroll
            for (int r = 0; r < 4; ++r) {
                float v = acc[r] + bi;
                if (res) v += res[(size_t)(m0 + r) * Nn + n];
                if (relu) v = fmaxf(v, 0.f);
                out[(size_t)(m0 + r) * Nn + n] = v;
            }
        }
    }
}

// ---------------- row LayerNorm over CS=384 ---------------------------------------
__global__ __launch_bounds__(64) void rowln_kernel(
    const float* in, float* out, const float* __restrict__ g, const float* __restrict__ b)
{
    int row = blockIdx.x;
    int lane = threadIdx.x;
    const float* x = in + (size_t)row * CS;
    float v[6];
    float s = 0.f, sq = 0.f;
    #pragma unroll
    for (int k = 0; k < 6; ++k) {
        v[k] = x[lane + k * 64];
        s += v[k]; sq += v[k] * v[k];
    }
    #pragma unroll
    for (int off = 32; off; off >>= 1) { s += __shfl_xor(s, off); sq += __shfl_xor(sq, off); }
    float mean = s * (1.0f / CS);
    float var = sq * (1.0f / CS) - mean * mean;
    float rstd = 1.0f / sqrtf(var + 1e-5f);
    float* o = out + (size_t)row * CS;
    #pragma unroll
    for (int k = 0; k < 6; ++k) {
        int c = lane + k * 64;
        o[c] = (v[k] - mean) * rstd * g[c] + b[c];
    }
}

// ---------------- z row stats (mean, rstd) over CZ=128 ----------------------------
__global__ __launch_bounds__(256) void zstats_kernel(const float* __restrict__ z, float* __restrict__ zstats)
{
    int wid = threadIdx.x >> 6;
    int lane = threadIdx.x & 63;
    size_t row = (size_t)blockIdx.x * 4 + wid;
    const float* x = z + row * CZ;
    float a = x[lane], b = x[lane + 64];
    float s = a + b, sq = a * a + b * b;
    #pragma unroll
    for (int off = 32; off; off >>= 1) { s += __shfl_xor(s, off); sq += __shfl_xor(sq, off); }
    if (lane == 0) {
        float mean = s * (1.0f / CZ);
        float var = sq * (1.0f / CZ) - mean * mean;
        zstats[row * 2] = mean;
        zstats[row * 2 + 1] = 1.0f / sqrtf(var + 1e-5f);
    }
}

// ---------------- pair bias (+mask) precompute: bpair[h][i][j] ---------------------
__global__ __launch_bounds__(256) void bpair_kernel(
    const float* __restrict__ z, const float* __restrict__ zstats,
    const float* __restrict__ lng, const float* __restrict__ lnb,
    const float* __restrict__ w_b, const float* __restrict__ b_b,
    const float* __restrict__ mask, float* __restrict__ bpair)
{
    __shared__ float wbs[HD][CZ];
    __shared__ float gs[CZ], bs[CZ];
    for (int idx = threadIdx.x; idx < HD * CZ; idx += 256) wbs[idx / CZ][idx % CZ] = w_b[idx];
    if (threadIdx.x < CZ) { gs[threadIdx.x] = lng[threadIdx.x]; bs[threadIdx.x] = lnb[threadIdx.x]; }
    __syncthreads();
    size_t row = (size_t)blockIdx.x * 256 + threadIdx.x;   // i*512 + j
    int i = (int)(row >> 9), j = (int)(row & 511);
    const float* zr = z + row * CZ;
    float m = zstats[row * 2], r = zstats[row * 2 + 1];
    float acc[HD];
    #pragma unroll
    for (int h = 0; h < HD; ++h) acc[h] = 0.f;
    for (int c = 0; c < CZ; c += 4) {
        float4 zv = *(const float4*)(zr + c);
        float zn0 = (zv.x - m) * r * gs[c] + bs[c];
        float zn1 = (zv.y - m) * r * gs[c+1] + bs[c+1];
        float zn2 = (zv.z - m) * r * gs[c+2] + bs[c+2];
        float zn3 = (zv.w - m) * r * gs[c+3] + bs[c+3];
        #pragma unroll
        for (int h = 0; h < HD; ++h)
            acc[h] += zn0 * wbs[h][c] + zn1 * wbs[h][c+1] + zn2 * wbs[h][c+2] + zn3 * wbs[h][c+3];
    }
    float mterm = INF_F * (mask[i] * mask[j] - 1.0f);
    #pragma unroll
    for (int h = 0; h < HD; ++h)
        bpair[((size_t)h * N_RES + i) * N_RES + j] = 0.57735026919f * (acc[h] + b_b[h]) + mterm;
}

// ---------------- pack qkv weights -------------------------------------------------
__global__ __launch_bounds__(256) void pack_kernel(
    const float* __restrict__ w_q, const float* __restrict__ w_kv,
    const float* __restrict__ w_qp, const float* __restrict__ w_kvp,
    const float* __restrict__ b_q, const float* __restrict__ b_kv,
    const float* __restrict__ b_qp, const float* __restrict__ b_kvp,
    float* __restrict__ wqkv, float* __restrict__ bqkv)
{
    int idx = blockIdx.x * 256 + threadIdx.x;
    if (idx < QKV_DIM * CS) {
        int rowi = idx / CS, col = idx % CS;
        float v;
        if (rowi < 192) v = w_q[rowi * CS + col];
        else if (rowi < 576) v = w_kv[(rowi - 192) * CS + col];
        else if (rowi < 720) v = w_qp[(rowi - 576) * CS + col];
        else v = w_kvp[(rowi - 720) * CS + col];
        wqkv[idx] = v;
    }
    if (idx < QKV_DIM) {
        float v;
        if (idx < 192) v = b_q[idx];
        else if (idx < 576) v = b_kv[idx - 192];
        else if (idx < 720) v = b_qp[idx - 576];
        else v = b_kvp[idx - 720];
        bqkv[idx] = v;
    }
}

// ---------------- init quats (normalize) and trans (/SCALE) ------------------------
__global__ void init_kernel(const float* __restrict__ rq, const float* __restrict__ rt,
                            float* __restrict__ quats, float* __restrict__ trans)
{
    int i = blockIdx.x * 256 + threadIdx.x;
    if (i < N_RES) {
        float w = rq[i*4], x = rq[i*4+1], y = rq[i*4+2], z = rq[i*4+3];
        float n = 1.0f / sqrtf(w*w + x*x + y*y + z*z);
        quats[i*4] = w*n; quats[i*4+1] = x*n; quats[i*4+2] = y*n; quats[i*4+3] = z*n;
        trans[i*3] = rt[i*3] * 0.1f; trans[i*3+1] = rt[i*3+1] * 0.1f; trans[i*3+2] = rt[i*3+2] * 0.1f;
    }
}

// ---------------- point transforms + vcat assembly (R from quats inline) ----------
__global__ __launch_bounds__(192) void transform_kernel(
    const float* __restrict__ qkv, const float* __restrict__ quats, const float* __restrict__ trans,
    float* __restrict__ qpts, float* __restrict__ kpts, float* __restrict__ vcat)
{
    int i = blockIdx.x, t = threadIdx.x;
    float R[9];
    quat_rot(quats[i*4], quats[i*4+1], quats[i*4+2], quats[i*4+3], R);
    float tx = trans[i*3], ty = trans[i*3+1], tz = trans[i*3+2];
    const float* row = qkv + (size_t)i * QKV_DIM;
    if (t < 48) {               // q points: t = h*4+pp
        float lx = row[576 + t], ly = row[576 + 48 + t], lz = row[576 + 96 + t];
        float gx = R[0]*lx + R[1]*ly + R[2]*lz + tx;
        float gy = R[3]*lx + R[4]*ly + R[5]*lz + ty;
        float gz = R[6]*lx + R[7]*ly + R[8]*lz + tz;
        float* o = qpts + (size_t)i * 144 + t * 3;
        o[0] = gx; o[1] = gy; o[2] = gz;
    }
    if (t < 144) {              // kv points: t = h*12+pp
        int h = t / 12, pp = t % 12;
        float lx = row[720 + t], ly = row[720 + 144 + t], lz = row[720 + 288 + t];
        float gx = R[0]*lx + R[1]*ly + R[2]*lz + tx;
        float gy = R[3]*lx + R[4]*ly + R[5]*lz + ty;
        float gz = R[6]*lx + R[7]*ly + R[8]*lz + tz;
        if (pp < 4) {
            float* o = kpts + (size_t)i * 144 + h * 12 + pp * 3;
            o[0] = gx; o[1] = gy; o[2] = gz;
        } else {
            float* o = vcat + (size_t)i * 480 + h * 40 + 16 + (pp - 4) * 3;
            o[0] = gx; o[1] = gy; o[2] = gz;
        }
    }
    {                           // v channels
        int h = t >> 4, c = t & 15;
        vcat[(size_t)i * 480 + h * 40 + c] = row[192 + h * 32 + 16 + c];
    }
}

// ---------------- FUSED attention: logits+softmax+o+opair+cat, one block per i ----
// Replaces attn/ogemm/opair/cat. a lives in LDS (als), never in global.
#define ALS_LD (N_RES + 1)   // 513: h-stride ≡1 mod 32 -> per-h bank spread
__global__ __launch_bounds__(512) void fused_attn_kernel(
    const float* __restrict__ qkv, const float* __restrict__ qpts, const float* __restrict__ kpts,
    const float* __restrict__ bpair, const float* __restrict__ head_weights,
    const float* __restrict__ z, const float* __restrict__ zstats,
    const float* __restrict__ lng, const float* __restrict__ lnb,
    const float* __restrict__ vcat, const float* __restrict__ quats, const float* __restrict__ trans,
    float* __restrict__ cat)
{
    int i = blockIdx.x;
    int t = threadIdx.x;              // phase 1: t = j
    __shared__ float als[HD][ALS_LD]; // ~24.6 KB
    __shared__ float qs[HD * CH];
    __shared__ float qp[144];
    __shared__ float shw[HD];
    __shared__ float red[HD][8];
    __shared__ float o_lds[480];
    __shared__ float zst[N_RES * 2];  // 4 KB

    if (t < 192) qs[t] = qkv[(size_t)i * QKV_DIM + t];
    else if (t < 336) qp[t - 192] = qpts[(size_t)i * 144 + (t - 192)];
    else if (t < 348) {
        float x = head_weights[t - 336];
        float sp = (x > 20.f) ? x : log1pf(expf(x));
        shw[t - 336] = sp * 0.13608276348f;   // softplus(hw) * sqrt(1/54)
    }
    for (int idx = t; idx < N_RES * 2; idx += 512) zst[idx] = zstats[(size_t)i * N_RES * 2 + idx];
    __syncthreads();

    // ---- phase 1: logits for all 12 heads, thread t = key index j ----
    float x[HD];
    {
        const float* kr = qkv + (size_t)t * QKV_DIM + 192;
        const float* kp = kpts + (size_t)t * 144;
        #pragma unroll
        for (int h = 0; h < HD; ++h) {
            float dot = 0.f;
            #pragma unroll
            for (int c = 0; c < CH; ++c) dot += qs[h * CH + c] * kr[h * 32 + c];
            float pt = 0.f;
            #pragma unroll
            for (int pc = 0; pc < 12; ++pc) { float d = qp[h * 12 + pc] - kp[h * 12 + pc]; pt += d * d; }
            x[h] = dot * 0.14433756730f + bpair[((size_t)h * N_RES + i) * N_RES + t] - 0.5f * shw[h] * pt;
        }
    }
    // ---- phase 2: per-head softmax over the 512 threads ----
    int lane = t & 63, wv = t >> 6;
    #pragma unroll
    for (int h = 0; h < HD; ++h) {
        float m = x[h];
        #pragma unroll
        for (int off = 32; off; off >>= 1) m = fmaxf(m, __shfl_xor(m, off));
        if (lane == 0) red[h][wv] = m;
    }
    __syncthreads();
    float ex[HD];
    #pragma unroll
    for (int h = 0; h < HD; ++h) {
        float m = red[h][0];
        #pragma unroll
        for (int w2 = 1; w2 < 8; ++w2) m = fmaxf(m, red[h][w2]);
        ex[h] = expf(x[h] - m);
    }
    __syncthreads();   // all reads of red(max) done before overwrite
    #pragma unroll
    for (int h = 0; h < HD; ++h) {
        float s = ex[h];
        #pragma unroll
        for (int off = 32; off; off >>= 1) s += __shfl_xor(s, off);
        if (lane == 0) red[h][wv] = s;
    }
    __syncthreads();
    #pragma unroll
    for (int h = 0; h < HD; ++h) {
        float s = red[h][0] + red[h][1] + red[h][2] + red[h][3]
                + red[h][4] + red[h][5] + red[h][6] + red[h][7];
        als[h][t] = ex[h] * (1.0f / s);
    }
    __syncthreads();

    // ---- phase 3: o[h][40] = sum_j a[h][j] * vcat[j][h][n] (t<480: h=t/40,n=t%40) ----
    if (t < 480) {
        int h = t / 40, n = t % 40;
        float a0 = 0.f, a1 = 0.f, a2 = 0.f, a3 = 0.f;
        const float* vb = vcat + h * 40 + n;
        for (int j = 0; j < N_RES; j += 4) {
            a0 += als[h][j]     * vb[(size_t)(j)     * 480];
            a1 += als[h][j + 1] * vb[(size_t)(j + 1) * 480];
            a2 += als[h][j + 2] * vb[(size_t)(j + 2) * 480];
            a3 += als[h][j + 3] * vb[(size_t)(j + 3) * 480];
        }
        o_lds[t] = (a0 + a1) + (a2 + a3);
    }

    // ---- phase 4: opair; thread t -> c = t&127, heads {h0, h0+4, h0+8}, h0 = t>>7 ----
    {
        int c = t & 127;
        int h0 = t >> 7;   // 0..3
        float g = lng[c], b = lnb[c];
        float acc0 = 0.f, acc1 = 0.f, acc2 = 0.f;
        const float* zr = z + (size_t)i * N_RES * CZ + c;
        for (int j = 0; j < N_RES; ++j) {
            float m = zst[j * 2], r = zst[j * 2 + 1];
            float zn = (zr[(size_t)j * CZ] - m) * r * g + b;
            acc0 += als[h0][j] * zn;
            acc1 += als[h0 + 4][j] * zn;
            acc2 += als[h0 + 8][j] * zn;
        }
        float* o = cat + (size_t)i * CAT_DIM + 576;
        o[h0 * CZ + c] = acc0;
        o[(h0 + 4) * CZ + c] = acc1;
        o[(h0 + 8) * CZ + c] = acc2;
    }
    __syncthreads();   // o_lds complete

    // ---- phase 5: cat[0:576) ----
    float* crow = cat + (size_t)i * CAT_DIM;
    if (t < 192) {
        int h = t >> 4, c = t & 15;
        crow[t] = o_lds[h * 40 + c];
    } else if (t < 288) {
        int tt = t - 192;               // h*8 + p
        int h = tt >> 3, p = tt & 7;
        float R[9];
        quat_rot(quats[i*4], quats[i*4+1], quats[i*4+2], quats[i*4+3], R);
        float tx = trans[i*3], ty = trans[i*3+1], tz = trans[i*3+2];
        const float* og = o_lds + h * 40 + 16 + p * 3;
        float dx = og[0] - tx, dy = og[1] - ty, dz = og[2] - tz;
        float lx = R[0]*dx + R[3]*dy + R[6]*dz;   // rot^T
        float ly = R[1]*dx + R[4]*dy + R[7]*dz;
        float lz = R[2]*dx + R[5]*dy + R[8]*dz;
        crow[192 + tt] = lx;
        crow[288 + tt] = ly;
        crow[384 + tt] = lz;
        crow[480 + tt] = sqrtf(lx*lx + ly*ly + lz*lz + 1e-8f);
    }
}

// ---------------- backbone update (R from quats inline) ----------------------------
__global__ __launch_bounds__(256) void frame_kernel(
    const float* __restrict__ s, const float* __restrict__ w_bb, const float* __restrict__ b_bb,
    float* quats, float* trans, float* __restrict__ frames_out)
{
    int lane = threadIdx.x & 63;
    int i = (blockIdx.x * 256 + threadIdx.x) >> 6;
    const float* srow = s + (size_t)i * CS;
    float p[6];
    #pragma unroll
    for (int r = 0; r < 6; ++r) p[r] = 0.f;
    #pragma unroll
    for (int k = 0; k < 6; ++k) {
        int c = lane + k * 64;
        float sv = srow[c];
        #pragma unroll
        for (int r = 0; r < 6; ++r) p[r] += sv * w_bb[r * CS + c];
    }
    #pragma unroll
    for (int r = 0; r < 6; ++r)
        #pragma unroll
        for (int off = 32; off; off >>= 1) p[r] += __shfl_xor(p[r], off);
    if (lane == 0) {
        float u0 = p[0] + b_bb[0], u1 = p[1] + b_bb[1], u2 = p[2] + b_bb[2];
        float u3 = p[3] + b_bb[3], u4 = p[4] + b_bb[4], u5 = p[5] + b_bb[5];
        float qw = quats[i*4], qx = quats[i*4+1], qy = quats[i*4+2], qz = quats[i*4+3];
        float R[9];
        quat_rot(qw, qx, qy, qz, R);
        float nw = qw - qx*u0 - qy*u1 - qz*u2;
        float nx = qw*u0 + qx + qy*u2 - qz*u1;
        float ny = qw*u1 - qx*u2 + qy + qz*u0;
        float nz = qw*u2 + qx*u1 - qy*u0 + qz;
        float n = 1.0f / sqrtf(nw*nw + nx*nx + ny*ny + nz*nz);
        nw *= n; nx *= n; ny *= n; nz *= n;
        float t0 = trans[i*3+0] + R[0]*u3 + R[1]*u4 + R[2]*u5;
        float t1 = trans[i*3+1] + R[3]*u3 + R[4]*u4 + R[5]*u5;
        float t2 = trans[i*3+2] + R[6]*u3 + R[7]*u4 + R[8]*u5;
        quats[i*4] = nw; quats[i*4+1] = nx; quats[i*4+2] = ny; quats[i*4+3] = nz;
        trans[i*3] = t0; trans[i*3+1] = t1; trans[i*3+2] = t2;
        float* f = frames_out + (size_t)i * 7;
        f[0] = nw; f[1] = nx; f[2] = ny; f[3] = nz;
        f[4] = t0 * 10.f; f[5] = t1 * 10.f; f[6] = t2 * 10.f;
    }
}

extern "C" void kernel_launch(void* const* d_in, const int* in_sizes, int n_in,
                              void* d_out, int out_size, void* d_ws, size_t ws_size,
                              hipStream_t stream)
{
    const float* s_in  = (const float*)d_in[0];
    const float* z     = (const float*)d_in[1];
    const float* rq    = (const float*)d_in[2];
    const float* rt    = (const float*)d_in[3];
    const float* mask  = (const float*)d_in[4];
    const float* ln_s_g = (const float*)d_in[5];
    const float* ln_s_b = (const float*)d_in[6];
    const float* ln_z_g = (const float*)d_in[7];
    const float* ln_z_b = (const float*)d_in[8];
    const float* w_in  = (const float*)d_in[9];
    const float* b_in  = (const float*)d_in[10];
    const float* w_q   = (const float*)d_in[11];
    const float* b_q   = (const float*)d_in[12];
    const float* w_kv  = (const float*)d_in[13];
    const float* b_kv  = (const float*)d_in[14];
    const float* w_qp  = (const float*)d_in[15];
    const float* b_qp  = (const float*)d_in[16];
    const float* w_kvp = (const float*)d_in[17];
    const float* b_kvp = (const float*)d_in[18];
    const float* w_b   = (const float*)d_in[19];
    const float* b_b   = (const float*)d_in[20];
    const float* head_weights = (const float*)d_in[21];
    const float* w_o   = (const float*)d_in[22];
    const float* b_o   = (const float*)d_in[23];
    const float* ln_ipa_g = (const float*)d_in[24];
    const float* ln_ipa_b = (const float*)d_in[25];
    const float* ln_tr_g  = (const float*)d_in[26];
    const float* ln_tr_b  = (const float*)d_in[27];
    const float* w_t1  = (const float*)d_in[28];
    const float* b_t1  = (const float*)d_in[29];
    const float* w_t2  = (const float*)d_in[30];
    const float* b_t2  = (const float*)d_in[31];
    const float* w_t3  = (const float*)d_in[32];
    const float* b_t3  = (const float*)d_in[33];
    const float* w_bb  = (const float*)d_in[34];
    const float* b_bb  = (const float*)d_in[35];

    float* ws = (float*)d_ws;
    size_t off = 0;
    auto alloc = [&](size_t n) { float* p = ws + off; off += n; return p; };
    float* s_tmp   = alloc((size_t)N_RES * CS);
    float* t1      = alloc((size_t)N_RES * CS);
    float* t2      = alloc((size_t)N_RES * CS);
    float* zstats  = alloc((size_t)N_RES * N_RES * 2);
    float* bpair   = alloc((size_t)HD * N_RES * N_RES);
    float* qkv_all = alloc((size_t)N_RES * QKV_DIM);
    float* qpts    = alloc((size_t)N_RES * 144);
    float* kpts    = alloc((size_t)N_RES * 144);
    float* vcat    = alloc((size_t)N_RES * 480);
    float* cat     = alloc((size_t)N_RES * CAT_DIM);
    float* quats   = alloc((size_t)N_RES * 4);
    float* trans   = alloc((size_t)N_RES * 3 + 1);
    float* wqkv    = alloc((size_t)QKV_DIM * CS);
    float* bqkv    = alloc((size_t)QKV_DIM);
    float* s_cur   = alloc((size_t)N_RES * CS);
    (void)ws_size; (void)in_sizes; (void)n_in; (void)out_size;

    // ---- preamble ----
    init_kernel<<<2, 256, 0, stream>>>(rq, rt, quats, trans);
    rowln_kernel<<<N_RES, 64, 0, stream>>>(s_in, s_tmp, ln_s_g, ln_s_b);
    gemm_mfma<<<dim3(CS / 64, N_RES / 64), 256, 0, stream>>>(s_tmp, w_in, b_in, nullptr, s_cur, N_RES, CS, CS, 0);
    zstats_kernel<<<(N_RES * N_RES) / 4, 256, 0, stream>>>(z, zstats);
    bpair_kernel<<<(N_RES * N_RES) / 256, 256, 0, stream>>>(z, zstats, ln_z_g, ln_z_b, w_b, b_b, mask, bpair);
    pack_kernel<<<(QKV_DIM * CS + 255) / 256, 256, 0, stream>>>(w_q, w_kv, w_qp, w_kvp, b_q, b_kv, b_qp, b_kvp, wqkv, bqkv);

    float* frames = (float*)d_out;
    for (int it = 0; it < 8; ++it) {
        gemm_mfma<<<dim3(QKV_DIM / 64, N_RES / 64), 256, 0, stream>>>(s_cur, wqkv, bqkv, nullptr, qkv_all, N_RES, QKV_DIM, CS, 0);
        transform_kernel<<<N_RES, 192, 0, stream>>>(qkv_all, quats, trans, qpts, kpts, vcat);
        fused_attn_kernel<<<N_RES, 512, 0, stream>>>(qkv_all, qpts, kpts, bpair, head_weights,
                                                     z, zstats, ln_z_g, ln_z_b, vcat, quats, trans, cat);
        gemm_mfma<<<dim3(CS / 64, N_RES / 64), 256, 0, stream>>>(cat, w_o, b_o, s_cur, s_cur, N_RES, CS, CAT_DIM, 0);
        rowln_kernel<<<N_RES, 64, 0, stream>>>(s_cur, s_cur, ln_ipa_g, ln_ipa_b);
        gemm_mfma<<<dim3(CS / 64, N_RES / 64), 256, 0, stream>>>(s_cur, w_t1, b_t1, nullptr, t1, N_RES, CS, CS, 1);
        gemm_mfma<<<dim3(CS / 64, N_RES / 64), 256, 0, stream>>>(t1, w_t2, b_t2, nullptr, t2, N_RES, CS, CS, 1);
        gemm_mfma<<<dim3(CS / 64, N_RES / 64), 256, 0, stream>>>(t2, w_t3, b_t3, s_cur, s_cur, N_RES, CS, CS, 0);
        rowln_kernel<<<N_RES, 64, 0, stream>>>(s_cur, s_cur, ln_tr_g, ln_tr_b);
        frame_kernel<<<N_RES / 4, 256, 0, stream>>>(s_cur, w_bb, b_bb, quats, trans, frames + (size_t)it * N_RES * 7);
    }
    hipMemcpyAsync(frames + 8 * N_RES * 7, s_cur, sizeof(float) * N_RES * CS,
                   hipMemcpyDeviceToDevice, stream);
}